// Round 5
// baseline (306.558 us; speedup 1.0000x reference)
//
#include <hip/hip_runtime.h>
#include <stdint.h>
#include <float.h>

#define TBITS 0x40400000u      // abs-bits of 3.0f: speculative threshold
#define CAND_CAP (1u << 20)    // 1M candidates (4 MB of ws)
#define LBUF_CAP 4096          // per-block LDS staging
#define ABLOCKS 2048
#define ATHREADS 256

// ws layout (unsigned):
// [0] gcount  [1] inv_minkey (max over ~fkey, identity 0)  [2] flag (1 = spec OK)
// [16, 16+CAND_CAP) candidate abs-bit patterns

__device__ __forceinline__ unsigned fkey(float f) {
    unsigned u = __float_as_uint(f);
    return (u & 0x80000000u) ? ~u : (u | 0x80000000u);
}

__device__ __forceinline__ void ema_write(unsigned bits, unsigned inv_mk,
                                          const float* min_val, const float* max_val,
                                          const int* num_flag, float* out) {
    float maxcur = __uint_as_float(bits);
    unsigned mk = ~inv_mk;
    float mincur = (mk & 0x80000000u) ? __uint_as_float(mk & 0x7FFFFFFFu)
                                      : __uint_as_float(~mk);
    bool first = (*num_flag == 0);
    out[0] = first ? mincur : (0.9f * min_val[0] + 0.1f * mincur);
    out[1] = first ? maxcur : (0.9f * max_val[0] + 0.1f * maxcur);
}

// single-block rank-select over LDS histogram h[nb]; needs part[nb/32], res[2]
__device__ void bin_select(const unsigned* h, int nb, unsigned r,
                           unsigned* part, unsigned* res) {
    int np = nb / 32;
    if ((int)threadIdx.x < np) {
        unsigned s = 0;
        for (int j = 0; j < 32; ++j) s += h[threadIdx.x * 32 + j];
        part[threadIdx.x] = s;
    }
    __syncthreads();
    if (threadIdx.x == 0) {
        unsigned cum = 0;
        int seg = 0;
        for (; seg < np; ++seg) {
            if (cum + part[seg] >= r) break;
            cum += part[seg];
        }
        int b = seg * 32;
        for (;; ++b) {
            if (cum + h[b] >= r) break;
            cum += h[b];
        }
        res[0] = (unsigned)b;
        res[1] = r - cum;
    }
    __syncthreads();
}

// ---- pass 1: pure stream. min + speculative compaction of abs-bits >= TBITS ----
__global__ __launch_bounds__(ATHREADS, 8) void pass1_kernel(
    const float* __restrict__ in, long long n,
    unsigned* __restrict__ gcount, unsigned* __restrict__ inv_minkey,
    unsigned* __restrict__ cand) {
    __shared__ unsigned lbuf[LBUF_CAP];
    __shared__ unsigned lcnt;
    __shared__ unsigned lbase;
    __shared__ unsigned wmax[ATHREADS / 64];
    if (threadIdx.x == 0) lcnt = 0;
    __syncthreads();

    long long gtid = (long long)blockIdx.x * blockDim.x + threadIdx.x;
    long long gs = (long long)gridDim.x * blockDim.x;
    const float4* in4 = (const float4*)in;
    long long n4 = n >> 2;
    float mn = FLT_MAX;

#define PROC1(f)                                                        \
    {                                                                   \
        mn = fminf(mn, (f));                                            \
        unsigned u = __float_as_uint(f) & 0x7FFFFFFFu;                  \
        if (u >= TBITS) {                                               \
            unsigned lp = atomicAdd(&lcnt, 1u);                         \
            if (lp < LBUF_CAP) lbuf[lp] = u;                            \
            else {                                                      \
                unsigned gp = atomicAdd(gcount, 1u);                    \
                if (gp < CAND_CAP) cand[gp] = u;                        \
            }                                                           \
        }                                                               \
    }
#define PROC4(v) PROC1((v).x) PROC1((v).y) PROC1((v).z) PROC1((v).w)

    long long i = gtid;
    for (; i + 3 * gs < n4; i += 4 * gs) {
        float4 v0 = in4[i];
        float4 v1 = in4[i + gs];
        float4 v2 = in4[i + 2 * gs];
        float4 v3 = in4[i + 3 * gs];
        PROC4(v0) PROC4(v1) PROC4(v2) PROC4(v3)
    }
    for (; i < n4; i += gs) {
        float4 v = in4[i];
        PROC4(v)
    }
    for (long long t = (n4 << 2) + gtid; t < n; t += gs) {
        float f = in[t];
        PROC1(f)
    }

    // block min reduce (inverted key, identity 0)
    unsigned ik = ~fkey(mn);
    for (int off = 32; off > 0; off >>= 1)
        ik = max(ik, (unsigned)__shfl_down((int)ik, off));
    if ((threadIdx.x & 63) == 0) wmax[threadIdx.x >> 6] = ik;
    __syncthreads();
    if (threadIdx.x == 0) {
        unsigned m = wmax[0];
        for (int w = 1; w < ATHREADS / 64; ++w) m = max(m, wmax[w]);
        atomicMax(inv_minkey, m);
        lbase = atomicAdd(gcount, min(lcnt, (unsigned)LBUF_CAP));
    }
    __syncthreads();
    unsigned c = min(lcnt, (unsigned)LBUF_CAP);
    for (unsigned t = threadIdx.x; t < c; t += blockDim.x) {
        unsigned gp = lbase + t;
        if (gp < CAND_CAP) cand[gp] = lbuf[t];
    }
}

// ---- spec path: validate + 3-level radix select over candidates ----
__global__ __launch_bounds__(1024) void spec_final_kernel(
    const unsigned* __restrict__ cand, const unsigned* __restrict__ gcount,
    const unsigned* __restrict__ inv_minkey, unsigned* __restrict__ flag,
    long long n, unsigned k,
    const float* __restrict__ min_val, const float* __restrict__ max_val,
    const int* __restrict__ num_flag, float* __restrict__ out) {
    __shared__ unsigned h[2048];
    __shared__ unsigned part[64];
    __shared__ unsigned res[2];

    unsigned m = *gcount;
    long long below = n - (long long)m;  // elements strictly below T (by bits)
    bool ok = (m <= CAND_CAP) && (below <= (long long)k - 1);
    if (threadIdx.x == 0) *flag = ok ? 1u : 0u;
    __syncthreads();
    if (!ok) return;
    unsigned r = (unsigned)((long long)k - below);  // 1-indexed rank among cands

    // level 1: bits 30..20
    for (int i = threadIdx.x; i < 2048; i += blockDim.x) h[i] = 0;
    __syncthreads();
    for (unsigned i = threadIdx.x; i < m; i += blockDim.x)
        atomicAdd(&h[cand[i] >> 20], 1u);
    __syncthreads();
    bin_select(h, 2048, r, part, res);
    unsigned b1 = res[0];
    r = res[1];

    // level 2: bits 19..10
    for (int i = threadIdx.x; i < 2048; i += blockDim.x) h[i] = 0;
    __syncthreads();
    for (unsigned i = threadIdx.x; i < m; i += blockDim.x) {
        unsigned u = cand[i];
        if ((u >> 20) == b1) atomicAdd(&h[(u >> 10) & 1023u], 1u);
    }
    __syncthreads();
    bin_select(h, 1024, r, part, res);
    unsigned b2 = res[0];
    r = res[1];

    // level 3: bits 9..0
    for (int i = threadIdx.x; i < 2048; i += blockDim.x) h[i] = 0;
    __syncthreads();
    for (unsigned i = threadIdx.x; i < m; i += blockDim.x) {
        unsigned u = cand[i];
        if ((u >> 20) == b1 && ((u >> 10) & 1023u) == b2)
            atomicAdd(&h[u & 1023u], 1u);
    }
    __syncthreads();
    bin_select(h, 1024, r, part, res);

    if (threadIdx.x == 0)
        ema_write((b1 << 20) | (b2 << 10) | res[0], *inv_minkey,
                  min_val, max_val, num_flag, out);
}

// ---- exact fallback (single block, 3 full passes) — never taken for this data ----
__global__ __launch_bounds__(1024) void fallback_kernel(
    const float* __restrict__ in, long long n,
    const unsigned* __restrict__ flag, const unsigned* __restrict__ inv_minkey,
    unsigned k,
    const float* __restrict__ min_val, const float* __restrict__ max_val,
    const int* __restrict__ num_flag, float* __restrict__ out) {
    if (*flag) return;
    __shared__ unsigned h[2048];
    __shared__ unsigned part[64];
    __shared__ unsigned res[2];
    unsigned r = k;

    for (int i = threadIdx.x; i < 2048; i += blockDim.x) h[i] = 0;
    __syncthreads();
    for (long long i = threadIdx.x; i < n; i += blockDim.x)
        atomicAdd(&h[(__float_as_uint(in[i]) & 0x7FFFFFFFu) >> 20], 1u);
    __syncthreads();
    bin_select(h, 2048, r, part, res);
    unsigned b1 = res[0];
    r = res[1];

    for (int i = threadIdx.x; i < 2048; i += blockDim.x) h[i] = 0;
    __syncthreads();
    for (long long i = threadIdx.x; i < n; i += blockDim.x) {
        unsigned u = __float_as_uint(in[i]) & 0x7FFFFFFFu;
        if ((u >> 20) == b1) atomicAdd(&h[(u >> 10) & 1023u], 1u);
    }
    __syncthreads();
    bin_select(h, 1024, r, part, res);
    unsigned b2 = res[0];
    r = res[1];

    for (int i = threadIdx.x; i < 2048; i += blockDim.x) h[i] = 0;
    __syncthreads();
    for (long long i = threadIdx.x; i < n; i += blockDim.x) {
        unsigned u = __float_as_uint(in[i]) & 0x7FFFFFFFu;
        if ((u >> 20) == b1 && ((u >> 10) & 1023u) == b2)
            atomicAdd(&h[u & 1023u], 1u);
    }
    __syncthreads();
    bin_select(h, 1024, r, part, res);

    if (threadIdx.x == 0)
        ema_write((b1 << 20) | (b2 << 10) | res[0], *inv_minkey,
                  min_val, max_val, num_flag, out);
}

extern "C" void kernel_launch(void* const* d_in, const int* in_sizes, int n_in,
                              void* d_out, int out_size, void* d_ws, size_t ws_size,
                              hipStream_t stream) {
    const float* in = (const float*)d_in[0];
    const float* minv = (const float*)d_in[1];
    const float* maxv = (const float*)d_in[2];
    const int* flag_in = (const int*)d_in[3];
    float* out = (float*)d_out;

    long long n = (long long)in_sizes[0];
    // k = int(0.9999 * n), matching Python's double arithmetic + truncation
    unsigned k = (unsigned)(long long)(0.9999 * (double)n);

    unsigned* ws = (unsigned*)d_ws;
    unsigned* gcount = ws + 0;
    unsigned* inv_minkey = ws + 1;
    unsigned* flag = ws + 2;
    unsigned* cand = ws + 16;

    hipMemsetAsync(ws, 0, 16 * sizeof(unsigned), stream);
    pass1_kernel<<<ABLOCKS, ATHREADS, 0, stream>>>(in, n, gcount, inv_minkey, cand);
    spec_final_kernel<<<1, 1024, 0, stream>>>(cand, gcount, inv_minkey, flag,
                                              n, k, minv, maxv, flag_in, out);
    fallback_kernel<<<1, 1024, 0, stream>>>(in, n, flag, inv_minkey, k,
                                            minv, maxv, flag_in, out);
}